// Round 7
// baseline (979.178 us; speedup 1.0000x reference)
//
#include <hip/hip_runtime.h>

// Problem constants (static in the reference)
#define NN 1024
#define MM 64
#define BB 8
#define EE 63456   // sum_i min(i,64) = 2016 + 960*64
#define NPB 8      // nodes per block

// ws float layout
#define WS_WN    0        // Wn_eff 192x64 fp32 (rows: src 0..63 | dst 64..127 | edge 128..191)
#define WS_WE    12288    // We_eff 128x64 fp32 (rows: src 0..63 | edge 64..127)
#define WS_BN    20480    // bn_eff 64 fp32
#define WS_BE    20544    // be_eff 64 fp32
#define WS_B2H   20608    // B2 hi fragments: [4 nt][8 ks][64 lane][8 e] ushort (16384 us)
#define WS_B2L   28800    // B2 lo
#define WS_B5H   36992    // B5 hi: [2 nt][8 ks][64 lane][8 e] ushort (8192 us)
#define WS_B5L   41088    // B5 lo

using short8 = __attribute__((ext_vector_type(8))) short;
using f32x16 = __attribute__((ext_vector_type(16))) float;

__device__ __forceinline__ unsigned bf16_rne(float x) {
    unsigned u = __float_as_uint(x);
    return (u + 0x7fffu + ((u >> 16) & 1u)) >> 16;
}

// Prep 1: collapse the inner linear pairs (no inner ReLU in the reference!).
__global__ __launch_bounds__(64)
void collapse_kernel(
    const float* __restrict__ Wn1, const float* __restrict__ bn1,
    const float* __restrict__ Wn2, const float* __restrict__ bn2,
    const float* __restrict__ We1, const float* __restrict__ be1,
    const float* __restrict__ We2, const float* __restrict__ be2,
    float* __restrict__ ws)
{
    const int r = blockIdx.x;
    const int n = threadIdx.x;
    if (r < 192) {
        float acc = 0.f;
#pragma unroll 16
        for (int t = 0; t < 128; ++t) acc += Wn1[r * 128 + t] * Wn2[t * 64 + n];
        ws[WS_WN + r * 64 + n] = acc;
    } else if (r < 320) {
        const int rr = r - 192;
        float acc = 0.f;
#pragma unroll 16
        for (int t = 0; t < 128; ++t) acc += We1[rr * 128 + t] * We2[t * 64 + n];
        ws[WS_WE + rr * 64 + n] = acc;
    } else if (r == 320) {
        float acc = bn2[n];
#pragma unroll 16
        for (int t = 0; t < 128; ++t) acc += bn1[t] * Wn2[t * 64 + n];
        ws[WS_BN + n] = acc;
    } else {
        float acc = be2[n];
#pragma unroll 16
        for (int t = 0; t < 128; ++t) acc += be1[t] * We2[t * 64 + n];
        ws[WS_BE + n] = acc;
    }
}

// Prep 2: pack split-bf16 MFMA B-fragments (pure reformat).
// B-fragment (32x32x16): lane l holds n = nt*32+(l&31), k = ks*16+(l>>5)*8+e.
__global__ void pack_kernel(const float* __restrict__ Wef, float* __restrict__ ws)
{
    int idx = blockIdx.x * 256 + threadIdx.x;
    if (idx >= 24576) return;
    float v; int pos, offh, offl;
    if (idx < 16384) {
        int e = idx & 7, l = (idx >> 3) & 63, ks = (idx >> 9) & 7, nt = idx >> 12;
        int k = ks * 16 + (l >> 5) * 8 + e;
        int n = nt * 32 + (l & 31);
        if (n < 64) {
            int r = (k < 64) ? k : (64 + k);
            v = ws[WS_WN + r * 64 + n];
        } else {
            v = ws[WS_WE + k * 64 + (n - 64)];
        }
        pos = idx; offh = WS_B2H; offl = WS_B2L;
    } else {
        int t2 = idx - 16384;
        int e = t2 & 7, l = (t2 >> 3) & 63, ks = (t2 >> 9) & 7, nt = t2 >> 12;
        int k = ks * 16 + (l >> 5) * 8 + e;
        int n = nt * 32 + (l & 31);
        v = Wef[k * 64 + n];
        pos = t2; offh = WS_B5H; offl = WS_B5L;
    }
    unsigned hh = bf16_rne(v);
    unsigned ll = bf16_rne(v - __uint_as_float(hh << 16));
    ((unsigned short*)(ws + offh))[pos] = (unsigned short)hh;
    ((unsigned short*)(ws + offl))[pos] = (unsigned short)ll;
}

// Main: 256 threads (4 waves) per block; each block processes NPB=8 consecutive
// nodes of one batch. Per-block invariants held in REGISTERS across the node
// loop: phase-2 B fragments (16/wave), phase-5 zz fragments (8, n-waves),
// Wnf column slice (64, e-waves). VGPR cap 256 (launch_bounds(256,2): pool is
// 512/SIMD — R6 lesson). 4 barriers/node. T14 staging split: node t+1 loads
// issued post-B2, LDS-written post-Bread.
__global__ __launch_bounds__(256, 2)
void main_kernel(const float* __restrict__ nodes,
                 const float* __restrict__ edges,
                 const float* __restrict__ ws,
                 const float* __restrict__ Wnf,   // W_nodes (128x64) fp32
                 const float* __restrict__ bias,  // bias_edges (64) — both outputs use it (ref quirk)
                 float* __restrict__ out)
{
    __shared__ __align__(16) unsigned short s_A[64 * 128];   // 16 KB A = [src||edge] bf16, swizzled
    __shared__ __align__(16) unsigned short s_pair[64 * 64]; // 8 KB pair_e bf16, swizzled
    __shared__ float s_dd[4 * 64];
    __shared__ float s_agg[64];
    __shared__ float s_dst[64];
    __shared__ float s_gn[64];

    const int tid = threadIdx.x;
    const int b   = blockIdx.x >> 7;
    const int i0  = (blockIdx.x & 127) * NPB;

    const int wv = tid >> 6, l = tid & 63, lo5 = l & 31, hi = l >> 5;
    const bool nw = wv < 2;            // waves 0,1: accn slabs + phase5 ; waves 2,3: acce + GEMV
    const int ntc = nw ? wv : (wv - 2);
    const int r0 = lo5, r1 = 32 + lo5;

    // ---- held per-block register state ----
    short8 pbh[8], pbl[8];             // phase-2 B fragments for this wave's slab
    {
        const unsigned short* Bh = (const unsigned short*)(ws + WS_B2H);
        const unsigned short* Bl = (const unsigned short*)(ws + WS_B2L);
#pragma unroll
        for (int ks = 0; ks < 8; ++ks) {
            pbh[ks] = *(const short8*)&Bh[((wv * 8 + ks) * 64 + l) * 8];
            pbl[ks] = *(const short8*)&Bl[((wv * 8 + ks) * 64 + l) * 8];
        }
    }
    short8 qzh[4], qzl[4];             // phase-5 zz fragments (n-waves only)
    if (nw) {
        const unsigned short* Bh = (const unsigned short*)(ws + WS_B5H);
        const unsigned short* Bl = (const unsigned short*)(ws + WS_B5L);
#pragma unroll
        for (int kk = 0; kk < 4; ++kk) {
            qzh[kk] = *(const short8*)&Bh[((ntc * 8 + kk) * 64 + l) * 8];
            qzl[kk] = *(const short8*)&Bl[((ntc * 8 + kk) * 64 + l) * 8];
        }
    }
    float wnf[64];                     // e-waves: held Wnf column slice
    if (!nw) {
        const int rof = (wv == 2) ? 0 : 64;   // wave2: agg rows 0..63 ; wave3: dst rows 64..127
#pragma unroll
        for (int c = 0; c < 64; ++c) wnf[c] = Wnf[(rof + c) * 64 + l];
    }
    const float bnv = nw ? ws[WS_BN + wv * 32 + lo5] : ws[WS_BE + ntc * 32 + lo5];
    const float bsv = bias[ntc * 32 + lo5];
    const float bge = bias[l];

    // ---- prologue: direct-stage node i0 ----
    {
        const int i = i0;
        const int w = (i < MM) ? i : MM;
        const long ns_ = (i <= 64) ? ((long)i * (i - 1)) / 2 : 2016L + (long)(i - 64) * 64;
        if (tid < 16)
            *(float4*)&s_dst[tid * 4] = ((const float4*)(nodes + ((size_t)b * NN + i) * 64))[tid];
        for (int idx = tid; idx < w * 16; idx += 256) {
            const int row = idx >> 4, q = idx & 15;
            const float* src = (q < 8)
                ? (nodes + ((size_t)b * NN + (i - w) + row) * 64 + q * 8)
                : (edges + ((size_t)b * EE + ns_ + row) * 64 + (q - 8) * 8);
            float4 x0 = *(const float4*)src;
            float4 x1 = *(const float4*)(src + 4);
            uint4 H;
            H.x = bf16_rne(x0.x) | (bf16_rne(x0.y) << 16);
            H.y = bf16_rne(x0.z) | (bf16_rne(x0.w) << 16);
            H.z = bf16_rne(x1.x) | (bf16_rne(x1.y) << 16);
            H.w = bf16_rne(x1.z) | (bf16_rne(x1.w) << 16);
            *(uint4*)&s_A[row * 128 + (q ^ (row & 15)) * 8] = H;
        }
    }
    __syncthreads();                                      // Bwrite(0)

#pragma unroll 1
    for (int t = 0; t < NPB; ++t) {
        const int i = i0 + t;
        const int w = (i < MM) ? i : MM;
        const long ns_ = (i <= 64) ? ((long)i * (i - 1)) / 2 : 2016L + (long)(i - 64) * 64;

        // ---- dd partials (pre-B2): wave wv covers c in [wv*16, wv*16+16) ----
        {
            float a = 0.f;
#pragma unroll
            for (int cc = 0; cc < 16; ++cc) {
                const int c = wv * 16 + cc;
                a += s_dst[c] * ws[WS_WN + (64 + c) * 64 + l];
            }
            s_dd[wv * 64 + l] = a;
        }

        // ---- Phase 2: wave = slab wv (32 cols), both M-tiles; B held in regs ----
        f32x16 acc0 = {}, acc1 = {};
#pragma unroll
        for (int ks = 0; ks < 8; ++ks) {
            const int u = ks * 2 + hi;
            short8 a0 = *(const short8*)&s_A[r0 * 128 + (u ^ (r0 & 15)) * 8];
            short8 a1 = *(const short8*)&s_A[r1 * 128 + (u ^ (r1 & 15)) * 8];
            acc0 = __builtin_amdgcn_mfma_f32_32x32x16_bf16(a0, pbh[ks], acc0, 0, 0, 0);
            acc0 = __builtin_amdgcn_mfma_f32_32x32x16_bf16(a0, pbl[ks], acc0, 0, 0, 0);
            acc1 = __builtin_amdgcn_mfma_f32_32x32x16_bf16(a1, pbh[ks], acc1, 0, 0, 0);
            acc1 = __builtin_amdgcn_mfma_f32_32x32x16_bf16(a1, pbl[ks], acc1, 0, 0, 0);
        }

        if (!nw) {
            // pair_e = relu(acce + be) -> bf16 -> s_pair (rows >= w zeroed)
            const int fp = ntc * 32 + lo5, ufp = fp >> 3, fofs = fp & 7;
#pragma unroll
            for (int reg = 0; reg < 16; ++reg) {
                const int rr = (reg & 3) + 8 * (reg >> 2) + 4 * hi;
                {
                    float p = (rr < w) ? fmaxf(acc0[reg] + bnv, 0.f) : 0.f;
                    s_pair[rr * 64 + ((ufp ^ (rr & 7)) << 3) + fofs] = (unsigned short)bf16_rne(p);
                }
                {
                    const int j2 = 32 + rr;
                    float p = (j2 < w) ? fmaxf(acc1[reg] + bnv, 0.f) : 0.f;
                    s_pair[j2 * 64 + ((ufp ^ (j2 & 7)) << 3) + fofs] = (unsigned short)bf16_rne(p);
                }
            }
        }
        __syncthreads();                                  // B2 (pair + dd ready)

        // ---- issue node t+1 staging loads (consumed post-Bread) ----
        float4 st[8]; float4 stdv;
        int w1 = 0;
        if (t + 1 < NPB) {
            const int i1 = i + 1;
            w1 = (i1 < MM) ? i1 : MM;
            const long ns1 = (i1 <= 64) ? ((long)i1 * (i1 - 1)) / 2 : 2016L + (long)(i1 - 64) * 64;
            if (tid < 16)
                stdv = ((const float4*)(nodes + ((size_t)b * NN + i1) * 64))[tid];
#pragma unroll
            for (int u = 0; u < 4; ++u) {
                const int idx = tid + u * 256;
                if (idx < w1 * 16) {
                    const int row = idx >> 4, q = idx & 15;
                    const float* src = (q < 8)
                        ? (nodes + ((size_t)b * NN + (i1 - w1) + row) * 64 + q * 8)
                        : (edges + ((size_t)b * EE + ns1 + row) * 64 + (q - 8) * 8);
                    st[2 * u]     = *(const float4*)src;
                    st[2 * u + 1] = *(const float4*)(src + 4);
                }
            }
        }

        short8 qeh[4], qel[4];   // phase-5 ze fragments (per node; issued pre-B3, used post-B3)
        if (nw) {
            const unsigned short* Bh = (const unsigned short*)(ws + WS_B5H);
            const unsigned short* Bl = (const unsigned short*)(ws + WS_B5L);
#pragma unroll
            for (int kk = 0; kk < 4; ++kk) {
                qeh[kk] = *(const short8*)&Bh[((ntc * 8 + 4 + kk) * 64 + l) * 8];
                qel[kk] = *(const short8*)&Bl[((ntc * 8 + 4 + kk) * 64 + l) * 8];
            }
            // accn reduce: agg[f] = sum_{j<w} relu(C + dd[f])
            const int f = wv * 32 + lo5;
            const float dd = bnv + s_dd[f] + s_dd[64 + f] + s_dd[128 + f] + s_dd[192 + f];
            float sum = 0.f;
#pragma unroll
            for (int reg = 0; reg < 16; ++reg) {
                const int rr = (reg & 3) + 8 * (reg >> 2) + 4 * hi;
                if (rr < w)      sum += fmaxf(acc0[reg] + dd, 0.f);
                if (32 + rr < w) sum += fmaxf(acc1[reg] + dd, 0.f);
            }
            sum += __shfl_xor(sum, 32);
            if (hi == 0) s_agg[f] = sum;
        } else if (wv == 3) {
            // dst-half GEMV partial (only needs s_dst)
            float s3 = 0.f;
#pragma unroll 8
            for (int c = 0; c < 64; ++c) s3 += s_dst[c] * wnf[c];
            s_gn[l] = s3;
        }
        __syncthreads();                                  // B3 (s_agg ready)

        float s2 = 0.f;
        float pz0[16], pz1[16], base0[4], base1[4], tot0 = 0.f;
        f32x16 ze0 = {}, ze1 = {};
        if (nw) {
            // zz = pair @ Wef[0:64]
            f32x16 zz0 = {}, zz1 = {};
#pragma unroll
            for (int kk = 0; kk < 4; ++kk) {
                const int ku = kk * 2 + hi;
                short8 a0 = *(const short8*)&s_pair[r0 * 64 + ((ku ^ (r0 & 7)) << 3)];
                short8 a1 = *(const short8*)&s_pair[r1 * 64 + ((ku ^ (r1 & 7)) << 3)];
                zz0 = __builtin_amdgcn_mfma_f32_32x32x16_bf16(a0, qzh[kk], zz0, 0, 0, 0);
                zz0 = __builtin_amdgcn_mfma_f32_32x32x16_bf16(a0, qzl[kk], zz0, 0, 0, 0);
                zz1 = __builtin_amdgcn_mfma_f32_32x32x16_bf16(a1, qzh[kk], zz1, 0, 0, 0);
                zz1 = __builtin_amdgcn_mfma_f32_32x32x16_bf16(a1, qzl[kk], zz1, 0, 0, 0);
            }
            // in-register exclusive prefix over 64 rows
            float G[4];
#pragma unroll
            for (int g = 0; g < 4; ++g) {
                float a0 = zz0[g * 4], a1 = zz0[g * 4 + 1], a2 = zz0[g * 4 + 2], a3 = zz0[g * 4 + 3];
                pz0[g * 4] = 0.f; pz0[g * 4 + 1] = a0; pz0[g * 4 + 2] = a0 + a1; pz0[g * 4 + 3] = a0 + a1 + a2;
                G[g] = a0 + a1 + a2 + a3;
            }
            float run = 0.f;
#pragma unroll
            for (int g = 0; g < 4; ++g) {
                float Gp = __shfl_xor(G[g], 32);
                base0[g] = run + (hi ? Gp : 0.f);
                run += G[g] + Gp;
            }
            tot0 = run;
#pragma unroll
            for (int g = 0; g < 4; ++g) {
                float a0 = zz1[g * 4], a1 = zz1[g * 4 + 1], a2 = zz1[g * 4 + 2], a3 = zz1[g * 4 + 3];
                pz1[g * 4] = 0.f; pz1[g * 4 + 1] = a0; pz1[g * 4 + 2] = a0 + a1; pz1[g * 4 + 3] = a0 + a1 + a2;
                G[g] = a0 + a1 + a2 + a3;
            }
            run = 0.f;
#pragma unroll
            for (int g = 0; g < 4; ++g) {
                float Gp = __shfl_xor(G[g], 32);
                base1[g] = run + (hi ? Gp : 0.f);
                run += G[g] + Gp;
            }
            // ze = edge @ Wef[64:128] (reads s_A edge half)
#pragma unroll
            for (int kk = 0; kk < 4; ++kk) {
                const int u = (4 + kk) * 2 + hi;
                short8 a0 = *(const short8*)&s_A[r0 * 128 + (u ^ (r0 & 15)) * 8];
                short8 a1 = *(const short8*)&s_A[r1 * 128 + (u ^ (r1 & 15)) * 8];
                ze0 = __builtin_amdgcn_mfma_f32_32x32x16_bf16(a0, qeh[kk], ze0, 0, 0, 0);
                ze0 = __builtin_amdgcn_mfma_f32_32x32x16_bf16(a0, qel[kk], ze0, 0, 0, 0);
                ze1 = __builtin_amdgcn_mfma_f32_32x32x16_bf16(a1, qeh[kk], ze1, 0, 0, 0);
                ze1 = __builtin_amdgcn_mfma_f32_32x32x16_bf16(a1, qel[kk], ze1, 0, 0, 0);
            }
            // out_edges = relu(prefix/max(j,1) + ze + bias)
            const int fcol = ntc * 32 + lo5;
            float* oute = out + (size_t)BB * NN * 64;
#pragma unroll
            for (int reg = 0; reg < 16; ++reg) {
                const int rr = (reg & 3) + 8 * (reg >> 2) + 4 * hi;
                if (rr < w) {
                    const float invj = (rr > 0) ? (1.0f / (float)rr) : 1.0f;
                    oute[((size_t)b * EE + ns_ + rr) * 64 + fcol] =
                        fmaxf((base0[reg >> 2] + pz0[reg]) * invj + ze0[reg] + bsv, 0.f);
                }
                const int j2 = 32 + rr;
                if (j2 < w) {
                    const float invj = 1.0f / (float)j2;
                    oute[((size_t)b * EE + ns_ + j2) * 64 + fcol] =
                        fmaxf((tot0 + base1[reg >> 2] + pz1[reg]) * invj + ze1[reg] + bsv, 0.f);
                }
            }
        } else if (wv == 2) {
            // agg-half GEMV (needs s_agg, valid since B3)
            const float invw = 1.0f / (float)((w > 0) ? w : 1);
#pragma unroll 8
            for (int c = 0; c < 64; ++c) s2 += (s_agg[c] * invw) * wnf[c];
        }
        __syncthreads();                                  // Bread (all LDS reads of node t done)

        if (wv == 2)
            out[((size_t)b * NN + i) * 64 + l] = fmaxf(s2 + s_gn[l] + bge, 0.f);

        // ---- write staged node t+1 into LDS ----
        if (t + 1 < NPB) {
            if (tid < 16) *(float4*)&s_dst[tid * 4] = stdv;
#pragma unroll
            for (int u = 0; u < 4; ++u) {
                const int idx = tid + u * 256;
                if (idx < w1 * 16) {
                    const int row = idx >> 4, q = idx & 15;
                    float4 x0 = st[2 * u], x1 = st[2 * u + 1];
                    uint4 H;
                    H.x = bf16_rne(x0.x) | (bf16_rne(x0.y) << 16);
                    H.y = bf16_rne(x0.z) | (bf16_rne(x0.w) << 16);
                    H.z = bf16_rne(x1.x) | (bf16_rne(x1.y) << 16);
                    H.w = bf16_rne(x1.z) | (bf16_rne(x1.w) << 16);
                    *(uint4*)&s_A[row * 128 + (q ^ (row & 15)) * 8] = H;
                }
            }
        }
        __syncthreads();                                  // Bwrite
    }
}

extern "C" void kernel_launch(void* const* d_in, const int* in_sizes, int n_in,
                              void* d_out, int out_size, void* d_ws, size_t ws_size,
                              hipStream_t stream) {
    const float* nodes = (const float*)d_in[0];
    const float* edges = (const float*)d_in[1];
    const float* Wn1  = (const float*)d_in[2];
    const float* bn1  = (const float*)d_in[3];
    const float* Wn2  = (const float*)d_in[4];
    const float* bn2  = (const float*)d_in[5];
    const float* We1  = (const float*)d_in[6];
    const float* be1  = (const float*)d_in[7];
    const float* We2  = (const float*)d_in[8];
    const float* be2  = (const float*)d_in[9];
    const float* Wnod = (const float*)d_in[10];
    const float* Wedg = (const float*)d_in[11];
    const float* bias = (const float*)d_in[12];
    float* ws = (float*)d_ws;
    float* out = (float*)d_out;

    hipLaunchKernelGGL(collapse_kernel, dim3(322), dim3(64), 0, stream,
                       Wn1, bn1, Wn2, bn2, We1, be1, We2, be2, ws);
    hipLaunchKernelGGL(pack_kernel, dim3(96), dim3(256), 0, stream, Wedg, ws);
    hipLaunchKernelGGL(main_kernel, dim3(BB * NN / NPB), dim3(256), 0, stream,
                       nodes, edges, ws, Wnod, bias, out);
}